// Round 7
// baseline (49.321 us; speedup 1.0000x reference)
//
#include <hip/hip_runtime.h>
#include <hip/hip_bf16.h>

#define N_LATENT 64
#define N_OUT    64

// One block (256 thr = 4 waves) per sample id s. Each lane pins A[s][:, lane]
// (64 floats) in VGPRs via an opaque asm keep-alive so the compiler cannot
// rematerialize the loads into the row loop (round-6 failure: VGPR=40 showed
// A was re-read from L1 per row -> ~1 GB L1 traffic, latency-bound).
// Block scans the 256 KB sid array (L2-broadcast) with double-buffered int4
// loads + ballot, computing matching rows on the fly.
__global__ __launch_bounds__(256, 4) void decoder_scan_kernel(
    const float* __restrict__ u,
    const int*   __restrict__ sid,
    const float* __restrict__ amat,
    const float* __restrict__ offsets,
    float*       __restrict__ out,
    int batch)
{
    const int s      = blockIdx.x;          // sample id
    const int lane   = threadIdx.x & 63;    // output column
    const int wave   = threadIdx.x >> 6;    // 0..3
    const int nwaves = blockDim.x >> 6;     // 4

    // ---- A column 'lane' into registers, pinned ----
    const float* __restrict__ A = amat + (size_t)s * (N_LATENT * N_OUT);
    float a[N_LATENT];
#pragma unroll
    for (int d = 0; d < N_LATENT; ++d) a[d] = A[d * N_OUT + lane];
#pragma unroll
    for (int d = 0; d < N_LATENT; ++d) {
        asm volatile("" : "+v"(a[d]));      // pin: no rematerialization
    }

    const float off = offsets[(size_t)s * N_OUT + lane];

    // ---- scan sid in int4, double-buffered ----
    const int4* __restrict__ sid4 = (const int4*)sid;
    const int n4       = batch >> 2;                        // batch % 4 == 0
    const int per_wave = (n4 + nwaves - 1) / nwaves;
    const int begin    = wave * per_wave;
    const int end      = (begin + per_wave < n4) ? (begin + per_wave) : n4;

    if (begin >= end) return;

    // prologue load (clamped; OOB lanes neutralized below)
    int c = begin + lane;
    int4 v = sid4[(c < n4) ? c : (n4 - 1)];
    if (c >= end) v = make_int4(-1, -1, -1, -1);

    for (int c0 = begin; c0 < end; c0 += 64) {
        // prefetch next iteration's int4 while processing this one
        const int cn = c0 + 64 + lane;
        int4 vn = sid4[(cn < n4) ? cn : (n4 - 1)];
        if (cn >= end) vn = make_int4(-1, -1, -1, -1);

        unsigned long long m[4];
        m[0] = __ballot(v.x == s);
        m[1] = __ballot(v.y == s);
        m[2] = __ballot(v.z == s);
        m[3] = __ballot(v.w == s);

#pragma unroll
        for (int e = 0; e < 4; ++e) {
            unsigned long long mm = m[e];
            while (mm) {                       // wave-uniform loop
                const int j = __builtin_ctzll(mm);
                mm &= mm - 1;
                const int b = 4 * (c0 + j) + e;            // matching row
                const float uv = u[(size_t)b * N_LATENT + lane];
                float acc = off;
#pragma unroll
                for (int d = 0; d < N_LATENT; ++d) {
                    const float ud = __int_as_float(
                        __builtin_amdgcn_readlane(__float_as_int(uv), d));
                    acc = fmaf(ud, a[d], acc);
                }
                out[(size_t)b * N_OUT + lane] = uv + acc;
            }
        }
        v = vn;
    }
}

extern "C" void kernel_launch(void* const* d_in, const int* in_sizes, int n_in,
                              void* d_out, int out_size, void* d_ws, size_t ws_size,
                              hipStream_t stream)
{
    const float* u       = (const float*)d_in[0];
    const int*   sid     = (const int*)d_in[1];
    const float* amat    = (const float*)d_in[2];
    const float* offsets = (const float*)d_in[3];
    float*       out     = (float*)d_out;

    const int batch    = in_sizes[0] / N_LATENT;            // 65536
    const int n_sample = in_sizes[2] / (N_LATENT * N_OUT);  // 1000

    decoder_scan_kernel<<<n_sample, 256, 0, stream>>>(
        u, sid, amat, offsets, out, batch);
}